// Round 6
// baseline (1297.318 us; speedup 1.0000x reference)
//
#include <hip/hip_runtime.h>

#define LSEQ 2048
#define DMOD 1024
#define NH   4
#define DH   256
#define NCH  64
#define CPAD 260

typedef unsigned short u16;
typedef short bf16x8 __attribute__((ext_vector_type(8)));
typedef float f32x4  __attribute__((ext_vector_type(4)));

#define MFMA16(a,b,c) __builtin_amdgcn_mfma_f32_16x16x32_bf16((a),(b),(c),0,0,0)

__device__ __forceinline__ float sigf(float x){ return 1.0f/(1.0f + expf(-x)); }

__device__ __forceinline__ u16 f2bf(float f){
  unsigned u = __float_as_uint(f);
  return (u16)((u + 0x7FFFu + ((u>>16)&1u)) >> 16);
}
__device__ __forceinline__ unsigned pk2(float a, float b){
  return (unsigned)f2bf(a) | ((unsigned)f2bf(b) << 16);
}
__device__ __forceinline__ float bf2f(u16 x){ return __uint_as_float(((unsigned)x)<<16); }

__device__ __forceinline__ void stage16(const void* g, void* l){
  __builtin_amdgcn_global_load_lds((const __attribute__((address_space(1))) unsigned*)g,
                                   (__attribute__((address_space(3))) unsigned*)l, 16, 0, 0);
}

// ---------------- merged fp32 -> bf16 convert (hidden + 4 weights) ----------------
__global__ __launch_bounds__(256) void cvt_all(
    const float* __restrict__ hidden, const float* __restrict__ Wq,
    const float* __restrict__ Wk, const float* __restrict__ Wv,
    const float* __restrict__ Wo, u16* __restrict__ hidb,
    u16* __restrict__ wqkvb, u16* __restrict__ wob)
{
  const int i4 = blockIdx.x*256 + threadIdx.x;   // 1.5M float4s
  const int e = i4*4;
  const float* src; u16* dst; int off;
  if (e < 2*1048576)      { src = hidden; dst = hidb;  off = e; }
  else if (e < 3*1048576) { src = Wq; dst = wqkvb; off = e - 2*1048576; }
  else if (e < 4*1048576) { src = Wk; dst = wqkvb + 1048576; off = e - 3*1048576; }
  else if (e < 5*1048576) { src = Wv; dst = wqkvb + 2*1048576; off = e - 4*1048576; }
  else                    { src = Wo; dst = wob; off = e - 5*1048576; }
  float4 v = *(const float4*)(src + off);
  *(uint2*)(dst + off) = make_uint2(pk2(v.x,v.y), pk2(v.z,v.w));
}

// ---------------- QKV GEMM: one launch, N=3072 split to 3 outputs ----------------
__global__ __launch_bounds__(256) void gemm_qkv(
    const u16* __restrict__ A, const u16* __restrict__ B,
    float* __restrict__ Cq, float* __restrict__ Ck, float* __restrict__ Cv)
{
  __shared__ __align__(16) u16 Asl[2][128][32];
  __shared__ __align__(16) u16 Bsl[2][128][32];
  const int i0 = blockIdx.x*128, j0 = blockIdx.y*128;
  const int t = threadIdx.x, lane = t & 63, wv = t >> 6;
  const int wm = wv >> 1, wn = wv & 1;
  const int li = lane & 15, g = lane >> 4;
  const int lr = lane >> 2, lc = lane & 3;
  f32x4 acc[4][4] = {};

  auto stageAB = [&](int buf, int kt){
    const int k0 = kt*32;
    #pragma unroll
    for (int c2=0;c2<2;c2++){
      const int row = wv*32 + c2*16 + lr;
      stage16(A + (size_t)(i0+row)*1024 + k0 + lc*8, &Asl[buf][wv*32 + c2*16][0]);
      stage16(B + (size_t)(j0+row)*1024 + k0 + lc*8, &Bsl[buf][wv*32 + c2*16][0]);
    }
  };

  int buf = 0;
  stageAB(0, 0);
  for (int kt=0; kt<32; kt++){
    __syncthreads();
    if (kt+1 < 32) stageAB(buf^1, kt+1);
    bf16x8 af[4], bf[4];
    #pragma unroll
    for (int mt=0;mt<4;mt++) af[mt] = *(const bf16x8*)&Asl[buf][wm*64+mt*16+li][g*8];
    #pragma unroll
    for (int nt=0;nt<4;nt++) bf[nt] = *(const bf16x8*)&Bsl[buf][wn*64+nt*16+li][g*8];
    #pragma unroll
    for (int mt=0;mt<4;mt++)
      #pragma unroll
      for (int nt=0;nt<4;nt++)
        acc[mt][nt] = MFMA16(af[mt], bf[nt], acc[mt][nt]);
    buf ^= 1;
  }
  float* C = (blockIdx.y < 8) ? Cq : (blockIdx.y < 16) ? Ck : Cv;
  const int jl = j0 & 1023;
  #pragma unroll
  for (int mt=0;mt<4;mt++){
    #pragma unroll
    for (int nt=0;nt<4;nt++){
      #pragma unroll
      for (int r=0;r<4;r++){
        const int row = i0 + wm*64 + mt*16 + g*4 + r;
        const int col = jl + wn*64 + nt*16 + li;
        C[(size_t)row*1024 + col] = acc[mt][nt][r];
      }
    }
  }
}

// ---------------- output GEMM: C[M][N]f32 = A[M][K] @ B[N][K]^T ----------------
__global__ __launch_bounds__(256) void gemm_bf16(
    const u16* __restrict__ A, const u16* __restrict__ B,
    float* __restrict__ C, int M, int N, int K)
{
  __shared__ __align__(16) u16 Asl[2][128][32];
  __shared__ __align__(16) u16 Bsl[2][128][32];
  const int i0 = blockIdx.x*128, j0 = blockIdx.y*128;
  const int t = threadIdx.x, lane = t & 63, wv = t >> 6;
  const int wm = wv >> 1, wn = wv & 1;
  const int li = lane & 15, g = lane >> 4;
  const int lr = lane >> 2, lc = lane & 3;
  f32x4 acc[4][4] = {};

  auto stageAB = [&](int buf, int kt){
    const int k0 = kt*32;
    #pragma unroll
    for (int c2=0;c2<2;c2++){
      const int row = wv*32 + c2*16 + lr;
      stage16(A + (size_t)(i0+row)*K + k0 + lc*8, &Asl[buf][wv*32 + c2*16][0]);
      stage16(B + (size_t)(j0+row)*K + k0 + lc*8, &Bsl[buf][wv*32 + c2*16][0]);
    }
  };

  int buf = 0;
  const int nk = K/32;
  stageAB(0, 0);
  for (int kt=0; kt<nk; kt++){
    __syncthreads();
    if (kt+1 < nk) stageAB(buf^1, kt+1);
    bf16x8 af[4], bf[4];
    #pragma unroll
    for (int mt=0;mt<4;mt++) af[mt] = *(const bf16x8*)&Asl[buf][wm*64+mt*16+li][g*8];
    #pragma unroll
    for (int nt=0;nt<4;nt++) bf[nt] = *(const bf16x8*)&Bsl[buf][wn*64+nt*16+li][g*8];
    #pragma unroll
    for (int mt=0;mt<4;mt++)
      #pragma unroll
      for (int nt=0;nt<4;nt++)
        acc[mt][nt] = MFMA16(af[mt], bf[nt], acc[mt][nt]);
    buf ^= 1;
  }
  #pragma unroll
  for (int mt=0;mt<4;mt++){
    #pragma unroll
    for (int nt=0;nt<4;nt++){
      #pragma unroll
      for (int r=0;r<4;r++){
        const int row = i0 + wm*64 + mt*16 + g*4 + r;
        const int col = j0 + wn*64 + nt*16 + li;
        C[(size_t)row*N + col] = acc[mt][nt][r];
      }
    }
  }
}

// ---------------- merged depthwise causal conv (K=4) + silu, bf16 out ----------------
__global__ __launch_bounds__(256) void conv_silu3(
    const float* __restrict__ tq, const float* __restrict__ tk, const float* __restrict__ tv,
    const float* __restrict__ wq, const float* __restrict__ wk, const float* __restrict__ wv2,
    u16* __restrict__ oq, u16* __restrict__ ok, u16* __restrict__ ov)
{
  const int idx = blockIdx.x*256 + threadIdx.x;
  const int which = idx >> 21;
  const int lidx = idx & ((1<<21)-1);
  const float* x = (which==0) ? tq : (which==1) ? tk : tv;
  const float* w = (which==0) ? wq : (which==1) ? wk : wv2;
  u16* y = (which==0) ? oq : (which==1) ? ok : ov;
  const int c = lidx & (DMOD-1);
  const int i = lidx >> 10;
  float4 wc = *(const float4*)(w + (size_t)c*4);
  float acc = wc.w * x[lidx];
  if (i >= 1) acc += wc.z * x[lidx -   DMOD];
  if (i >= 2) acc += wc.y * x[lidx - 2*DMOD];
  if (i >= 3) acc += wc.x * x[lidx - 3*DMOD];
  y[lidx] = f2bf(acc * sigf(acc));
}

// ---------------- beta (sigmoid) + 5-way gate probs per row ----------------
__global__ __launch_bounds__(256) void beta_gate(
    const float* __restrict__ hidden, const float* __restrict__ Wb,
    const float* __restrict__ gw, const float* __restrict__ gb,
    const float* __restrict__ logtemp, const float* __restrict__ epsp,
    float* __restrict__ betab, float* __restrict__ probs)
{
  const int i = blockIdx.x, t = threadIdx.x;
  float4 h4 = *(const float4*)(hidden + (size_t)i*DMOD + t*4);
  float part[24];
  #pragma unroll
  for (int o=0;o<24;o++){
    const float* wr = (o<4) ? (Wb + (size_t)o*DMOD) : (gw + (size_t)(o-4)*DMOD);
    float4 w4 = *(const float4*)(wr + t*4);
    part[o] = h4.x*w4.x + h4.y*w4.y + h4.z*w4.z + h4.w*w4.w;
  }
  __shared__ float red[24][4];
  __shared__ float fin[24];
  const int lane = t & 63, wv = t >> 6;
  #pragma unroll
  for (int o=0;o<24;o++){
    float vv = part[o];
    #pragma unroll
    for (int m=1;m<64;m<<=1) vv += __shfl_xor(vv, m, 64);
    if (lane == 0) red[o][wv] = vv;
  }
  __syncthreads();
  if (t < 24) fin[t] = red[t][0]+red[t][1]+red[t][2]+red[t][3];
  __syncthreads();
  if (t < NH){
    const int hh = t;
    betab[(size_t)i*NH + hh] = sigf(fin[hh]);
    float temp = expf(logtemp[hh]);
    float lg[5], mx = -1e30f;
    #pragma unroll
    for (int p=0;p<5;p++){ lg[p] = (fin[4+hh*5+p] + gb[hh*5+p]) / temp; mx = fmaxf(mx, lg[p]); }
    float ex[5], s = 0.f;
    #pragma unroll
    for (int p=0;p<5;p++){ ex[p] = expf(lg[p]-mx); s += ex[p]; }
    float eps = fminf(fmaxf(epsp[hh], 0.f), 0.2f);
    #pragma unroll
    for (int p=0;p<5;p++) probs[((size_t)i*NH+hh)*5 + p] = (ex[p]/s)*(1.f-5.f*eps) + eps;
  }
}

// ---------------- delta precompute: per (chunk, head), bf16 q/k/v inputs ----------------
__global__ __launch_bounds__(256) void delta_pre(
    const u16* __restrict__ q, const u16* __restrict__ k, const u16* __restrict__ v,
    const float* __restrict__ beta,
    u16* __restrict__ qbg, u16* __restrict__ wng, u16* __restrict__ kTg,
    u16* __restrict__ atg, float* __restrict__ ubuf)
{
  const int n = blockIdx.x, h = blockIdx.y;
  const int t = threadIdx.x;
  __shared__ float q_s[32][CPAD], k_s[32][CPAD], v_s[32][CPAD];
  __shared__ float T_s[32][32], Tb_s[32][32], M_s[32][32];
  __shared__ float rr[2][32][8];
  __shared__ float scl[2][32];
  __shared__ float bet_s[32];

  const int row = t >> 3, cq = t & 7;
  const size_t gb = (size_t)(n*32+row)*DMOD + h*DH + cq*32;
  const size_t cb = (size_t)(h*NCH+n)*32*256;
  const int sw = (row & 7) << 3;
  float psq = 0.f, psk = 0.f;
  #pragma unroll
  for (int x=0;x<4;x++){
    uint4 qa = *(const uint4*)(q + gb + x*8);
    uint4 ka = *(const uint4*)(k + gb + x*8);
    uint4 va = *(const uint4*)(v + gb + x*8);
    const unsigned qw[4] = {qa.x,qa.y,qa.z,qa.w};
    const unsigned kw[4] = {ka.x,ka.y,ka.z,ka.w};
    const unsigned vw[4] = {va.x,va.y,va.z,va.w};
    #pragma unroll
    for (int e=0;e<4;e++){
      float q0 = bf2f((u16)(qw[e]&0xffff)), q1 = bf2f((u16)(qw[e]>>16));
      float k0 = bf2f((u16)(kw[e]&0xffff)), k1 = bf2f((u16)(kw[e]>>16));
      float v0 = bf2f((u16)(vw[e]&0xffff)), v1 = bf2f((u16)(vw[e]>>16));
      q_s[row][cq*32+x*8+e*2]   = q0; q_s[row][cq*32+x*8+e*2+1] = q1;
      k_s[row][cq*32+x*8+e*2]   = k0; k_s[row][cq*32+x*8+e*2+1] = k1;
      v_s[row][cq*32+x*8+e*2]   = v0; v_s[row][cq*32+x*8+e*2+1] = v1;
      psq += q0*q0 + q1*q1;
      psk += k0*k0 + k1*k1;
    }
  }
  rr[0][row][cq] = psq; rr[1][row][cq] = psk;
  if (t < 32) bet_s[t] = beta[(size_t)(n*32+t)*NH + h];
  __syncthreads();
  if (t < 64){
    const int wh = t >> 5, r = t & 31;
    float s = 1e-6f;
    #pragma unroll
    for (int x=0;x<8;x++) s += rr[wh][r][x];
    scl[wh][r] = rsqrtf(s);
  }
  __syncthreads();
  {
    const float sq = scl[0][row], sk2 = scl[1][row];
    #pragma unroll
    for (int x=0;x<8;x++){
      float4 qa = *(float4*)&q_s[row][cq*32+x*4];
      qa.x*=sq; qa.y*=sq; qa.z*=sq; qa.w*=sq;
      *(float4*)&q_s[row][cq*32+x*4] = qa;
      *(uint2*)&qbg[cb + (size_t)row*256 + ((cq*32 + x*4) ^ sw)] =
          make_uint2(pk2(qa.x,qa.y), pk2(qa.z,qa.w));
      float4 ka = *(float4*)&k_s[row][cq*32+x*4];
      ka.x*=sk2; ka.y*=sk2; ka.z*=sk2; ka.w*=sk2;
      *(float4*)&k_s[row][cq*32+x*4] = ka;
    }
  }
  __syncthreads();
  // kT bf16 [dk=256][c=32], u32-col swizzle c2 ^ ((row&3)<<2)
  {
    unsigned* kp = (unsigned*)(kTg + ((size_t)(h*NCH+n)*256 + t)*32);
    #pragma unroll
    for (int c2=0;c2<16;c2++)
      kp[c2 ^ ((t&3)<<2)] = pk2(k_s[2*c2][t], k_s[2*c2+1][t]);
  }
  // M matrix
  {
    const int c = t >> 3, m0 = (t & 7)*4;
    float d0=0.f,d1=0.f,d2=0.f,d3=0.f;
    for (int kk=0;kk<DH;kk+=4){
      float4 a  = *(const float4*)&k_s[c][kk];
      float4 b0 = *(const float4*)&k_s[m0+0][kk];
      float4 b1 = *(const float4*)&k_s[m0+1][kk];
      float4 b2 = *(const float4*)&k_s[m0+2][kk];
      float4 b3 = *(const float4*)&k_s[m0+3][kk];
      d0 += a.x*b0.x + a.y*b0.y + a.z*b0.z + a.w*b0.w;
      d1 += a.x*b1.x + a.y*b1.y + a.z*b1.z + a.w*b1.w;
      d2 += a.x*b2.x + a.y*b2.y + a.z*b2.z + a.w*b2.w;
      d3 += a.x*b3.x + a.y*b3.y + a.z*b3.z + a.w*b3.w;
    }
    const float bc = bet_s[c];
    M_s[c][m0+0] = (m0+0 < c) ? bc*d0 : ((m0+0==c)?1.f:0.f);
    M_s[c][m0+1] = (m0+1 < c) ? bc*d1 : ((m0+1==c)?1.f:0.f);
    M_s[c][m0+2] = (m0+2 < c) ? bc*d2 : ((m0+2==c)?1.f:0.f);
    M_s[c][m0+3] = (m0+3 < c) ? bc*d3 : ((m0+3==c)?1.f:0.f);
  }
  __syncthreads();
  if (t < 32){
    const int j = t;
    for (int c=0;c<32;c++){
      float s = (c==j) ? 1.f : 0.f;
      for (int m=0;m<c;m++) s -= M_s[c][m]*T_s[m][j];
      T_s[c][j] = s;
    }
  }
  __syncthreads();
  {
    const int c = t >> 3, m0 = (t & 7)*4;
    #pragma unroll
    for (int x=0;x<4;x++) Tb_s[c][m0+x] = T_s[c][m0+x]*bet_s[m0+x];
  }
  __syncthreads();
  // w = Tb @ k_s (emit -w bf16, swizzled); u = Tb @ v_s (fp32)
  {
    const int colb = (t & 7)*4;
    float4 aw[8] = {};
    float4 au[8] = {};
    for (int m=0;m<32;m++){
      const float tb = Tb_s[row][m];
      #pragma unroll
      for (int y=0;y<8;y++){
        float4 kv = *(const float4*)&k_s[m][colb + y*32];
        float4 vv = *(const float4*)&v_s[m][colb + y*32];
        aw[y].x += tb*kv.x; aw[y].y += tb*kv.y; aw[y].z += tb*kv.z; aw[y].w += tb*kv.w;
        au[y].x += tb*vv.x; au[y].y += tb*vv.y; au[y].z += tb*vv.z; au[y].w += tb*vv.w;
      }
    }
    const size_t ob = (size_t)(n*32+row)*DMOD + h*DH + colb;
    #pragma unroll
    for (int y=0;y<8;y++){
      *(uint2*)&wng[cb + (size_t)row*256 + ((colb + y*32) ^ sw)] =
          make_uint2(pk2(-aw[y].x,-aw[y].y), pk2(-aw[y].z,-aw[y].w));
      *(float4*)(ubuf + ob + y*32) = au[y];
    }
  }
  // attn = tril(q k^T) bf16 [c][c'], swizzle m0 ^ ((c&3)<<3)
  {
    const int c = t >> 3, m0 = (t & 7)*4;
    float d0=0.f,d1=0.f,d2=0.f,d3=0.f;
    for (int kk=0;kk<DH;kk+=4){
      float4 a  = *(const float4*)&q_s[c][kk];
      float4 b0 = *(const float4*)&k_s[m0+0][kk];
      float4 b1 = *(const float4*)&k_s[m0+1][kk];
      float4 b2 = *(const float4*)&k_s[m0+2][kk];
      float4 b3 = *(const float4*)&k_s[m0+3][kk];
      d0 += a.x*b0.x + a.y*b0.y + a.z*b0.z + a.w*b0.w;
      d1 += a.x*b1.x + a.y*b1.y + a.z*b1.z + a.w*b1.w;
      d2 += a.x*b2.x + a.y*b2.y + a.z*b2.z + a.w*b2.w;
      d3 += a.x*b3.x + a.y*b3.y + a.z*b3.z + a.w*b3.w;
    }
    d0 = (m0+0 <= c) ? d0 : 0.f;
    d1 = (m0+1 <= c) ? d1 : 0.f;
    d2 = (m0+2 <= c) ? d2 : 0.f;
    d3 = (m0+3 <= c) ? d3 : 0.f;
    *(uint2*)&atg[((size_t)(h*NCH+n)*32 + c)*32 + (m0 ^ ((c&3)<<3))] =
        make_uint2(pk2(d0,d1), pk2(d2,d3));
  }
}

// ---------------- fused delta scan v5: 2 barriers/chunk ----------------
// 4 waves: cs = wv&1 (c-half), j = wv>>1 (op dk-half / uaT split / o-row split).
// Each wave: full-dk ua (redundant per j-pair), q@S dk-half, S dk-quarter wv in regs,
// attn@ua redundant. Dbuf gload_lds staging, counted vmcnt(2).
__global__ __launch_bounds__(256) void delta_scan_fused(
    const u16* __restrict__ qbg, const u16* __restrict__ wng,
    const u16* __restrict__ kTg, const u16* __restrict__ atg,
    const float* __restrict__ ubuf, float* __restrict__ dob)
{
  const int qd = blockIdx.x, h = blockIdx.y;
  const int t = threadIdx.x, lane = t & 63, wv = t >> 6;
  const int cs = wv & 1, j = wv >> 1;
  const int g = lane >> 4, li = lane & 15;
  const int swz = (li & 7) << 3;
  const int kswz = (li & 3) << 3;

  __shared__ __align__(16) unsigned char stg[2][53248];
  __shared__ __align__(16) u16 ST[16][264];
  __shared__ __align__(16) u16 uaT[16][40];
  __shared__ __align__(16) float pfo[2][2][64][4];   // [j][cs][lane][4]

  f32x4 S[4];
  #pragma unroll
  for (int i=0;i<4;i++) S[i] = (f32x4){0.f,0.f,0.f,0.f};
  for (int i=t; i<16*264; i+=256) (&ST[0][0])[i] = 0;

  auto issue_stage = [&](int nn, int b){
    char* L = (char*)&stg[b][0];
    const size_t cbB = (size_t)(h*NCH+nn)*16384;
    #pragma unroll
    for (int jj=0;jj<13;jj++){
      const int s = wv*13 + jj;
      if (s < 48){
        const char* gsc = (s<16) ? (const char*)wng + cbB + (size_t)s*1024
                       : (s<32) ? (const char*)qbg + cbB + (size_t)(s-16)*1024
                                : (const char*)kTg + cbB + (size_t)(s-32)*1024;
        stage16(gsc + (size_t)lane*16, L + s*1024);
      } else if (s < 50){
        stage16((const char*)atg + (size_t)(h*NCH+nn)*2048 + (size_t)(s-48)*1024 + (size_t)lane*16,
                L + 49152 + (s-48)*1024);
      } else {
        const int i2 = s - 50;
        stage16(ubuf + (size_t)(nn*32 + i2*16 + (lane>>2))*DMOD + h*DH + qd*16 + (lane&3)*4,
                L + 51200 + i2*1024);
      }
    }
  };

  issue_stage(0, 0);

  for (int n=0;n<NCH;n++){
    const int b = n & 1;
    if (n == 0) asm volatile("s_waitcnt vmcnt(0)" ::: "memory");
    else        asm volatile("s_waitcnt vmcnt(2)" ::: "memory");
    asm volatile("s_waitcnt lgkmcnt(0)" ::: "memory");
    __builtin_amdgcn_s_barrier();                       // B1: buffer + ST ready
    __builtin_amdgcn_sched_barrier(0);
    issue_stage((n+1 < NCH) ? n+1 : NCH-1, b^1);

    const char* L = (const char*)&stg[b][0];
    const u16*  wl = (const u16*)(L);
    const u16*  ql = (const u16*)(L + 16384);
    const u16*  kl = (const u16*)(L + 32768);
    const u16*  al = (const u16*)(L + 49152);
    const float* ul = (const float*)(L + 51200);

    // ---- full S^T B-frags ----
    bf16x8 Bs[8];
    #pragma unroll
    for (int kb=0;kb<8;kb++)
      Bs[kb] = *(const bf16x8*)&ST[li][kb*32 + g*8];

    // ---- ua = u - w @ S (full dk, c-half cs; chain split 2x4) ----
    f32x4 ua;
    #pragma unroll
    for (int r=0;r<4;r++)
      ua[r] = ul[(cs*16 + g*4 + r)*16 + li];
    f32x4 x2 = (f32x4){0.f,0.f,0.f,0.f};
    #pragma unroll
    for (int kb=0;kb<4;kb++){
      const int idx = (kb*32 + g*8) ^ swz;
      bf16x8 aw = *(const bf16x8*)&wl[(size_t)(cs*16+li)*256 + idx];
      ua = MFMA16(aw, Bs[kb], ua);
    }
    #pragma unroll
    for (int kb=4;kb<8;kb++){
      const int idx = (kb*32 + g*8) ^ swz;
      bf16x8 aw = *(const bf16x8*)&wl[(size_t)(cs*16+li)*256 + idx];
      x2 = MFMA16(aw, Bs[kb], x2);
    }
    #pragma unroll
    for (int r=0;r<4;r++) ua[r] += x2[r];

    // ---- op = q @ S (dk-half j, c-half cs) ----
    f32x4 op = (f32x4){0.f,0.f,0.f,0.f};
    #pragma unroll
    for (int kb2=0;kb2<4;kb2++){
      const int kb = j*4 + kb2;
      const int idx = (kb*32 + g*8) ^ swz;
      bf16x8 aq = *(const bf16x8*)&ql[(size_t)(cs*16+li)*256 + idx];
      op = MFMA16(aq, Bs[kb], op);
    }
    *(f32x4*)&pfo[j][cs][lane][0] = op;

    // ---- uaT split-write (j0: elems 0,1; j1: elems 2,3) ----
    if (j == 0) *(unsigned*)&uaT[li][cs*16 + g*4]     = pk2(ua[0], ua[1]);
    else        *(unsigned*)&uaT[li][cs*16 + g*4 + 2] = pk2(ua[2], ua[3]);
    asm volatile("s_waitcnt lgkmcnt(0)" ::: "memory");
    __builtin_amdgcn_s_barrier();                       // B2: uaT + pfo ready
    __builtin_amdgcn_sched_barrier(0);

    bf16x8 bu = *(const bf16x8*)&uaT[li][g*8];

    // ---- S += kT @ ua (dk-quarter wv) + ST refresh ----
    #pragma unroll
    for (int mtl=0;mtl<4;mtl++){
      const int rowk = (wv*4+mtl)*16 + li;
      bf16x8 a = *(const bf16x8*)&kl[(size_t)rowk*32 + ((g*8) ^ kswz)];
      S[mtl] = MFMA16(a, bu, S[mtl]);
    }
    #pragma unroll
    for (int mtl=0;mtl<4;mtl++)
      *(uint2*)&ST[li][(wv*4+mtl)*16 + g*4] =
          make_uint2(pk2(S[mtl][0],S[mtl][1]), pk2(S[mtl][2],S[mtl][3]));

    // ---- attn @ ua (redundant, own c-half) ----
    f32x4 atp = (f32x4){0.f,0.f,0.f,0.f};
    {
      bf16x8 a = *(const bf16x8*)&al[(size_t)(cs*16+li)*32 + ((g*8) ^ kswz)];
      atp = MFMA16(a, bu, atp);
    }

    // ---- o = op + pfo[other dk-half] + atp ; store rows r = j*2+r2 ----
    {
      f32x4 oq = *(const f32x4*)&pfo[j^1][cs][lane][0];
      const size_t ob = (size_t)(n*32 + cs*16)*DMOD + h*DH + qd*16 + li;
      #pragma unroll
      for (int r2=0;r2<2;r2++){
        const int r = j*2 + r2;
        dob[ob + (size_t)(g*4+r)*DMOD] = op[r] + oq[r] + atp[r];
      }
    }
  }
}

// ---------------- transpose FIR filters to [j][c] ----------------
__global__ void prep_fir(const float* __restrict__ fs, const float* __restrict__ fm,
                         const float* __restrict__ fl, float* __restrict__ fts,
                         float* __restrict__ ftm, float* __restrict__ ftl)
{
  const int idx = blockIdx.x*256 + threadIdx.x;
  if (idx < 63*1024){
    const int j = idx >> 10, c = idx & 1023;
    ftl[idx] = fl[(size_t)c*63 + j];
  } else if (idx < 78*1024){
    const int r = idx - 63*1024;
    const int j = r >> 10, c = r & 1023;
    ftm[r] = fm[(size_t)c*15 + j];
  } else {
    const int r = idx - 78*1024;
    const int j = r >> 10, c = r & 1023;
    fts[r] = fs[(size_t)c*3 + j];
  }
}

// ---------------- FIR + gated mix + RMSNorm, LDS-windowed (16 rows/block) ----------------
__global__ __launch_bounds__(256) void fir_mix(
    const u16* __restrict__ vb, const float* __restrict__ dout,
    const float* __restrict__ probs, const float* __restrict__ ftl,
    const float* __restrict__ ftm, const float* __restrict__ fts,
    const float* __restrict__ normw, u16* __restrict__ omixb)
{
  const int i0 = blockIdx.x*16, h = blockIdx.y;
  const int t = threadIdx.x;
  const int c = h*DH + t;
  __shared__ float vwin[78][256];
  __shared__ float red[16][4];

  for (int ll=0; ll<78; ll++){
    const int row = i0 - 62 + ll;
    vwin[ll][t] = (row >= 0) ? bf2f(vb[(size_t)row*DMOD + c]) : 0.f;
  }
  __syncthreads();

  float mixv[16];
  #pragma unroll
  for (int cch=0; cch<4; cch++){
    float as[4] = {0,0,0,0}, am[4] = {0,0,0,0}, alg[4] = {0,0,0,0};
    for (int jt=0; jt<63; jt++){
      const float f = ftl[(size_t)jt*DMOD + c];
      #pragma unroll
      for (int q2=0;q2<4;q2++) alg[q2] += f * vwin[cch*4+q2 + jt][t];
    }
    #pragma unroll
    for (int jt=0; jt<15; jt++){
      const float f = ftm[(size_t)jt*DMOD + c];
      #pragma unroll
      for (int q2=0;q2<4;q2++) am[q2] += f * vwin[cch*4+q2 + 48 + jt][t];
    }
    #pragma unroll
    for (int jt=0; jt<3; jt++){
      const float f = fts[(size_t)jt*DMOD + c];
      #pragma unroll
      for (int q2=0;q2<4;q2++) as[q2] += f * vwin[cch*4+q2 + 60 + jt][t];
    }
    #pragma unroll
    for (int q2=0;q2<4;q2++){
      const int ii = cch*4+q2;
      const int i = i0+ii;
      const float* pr = probs + ((size_t)i*NH + h)*5;
      const float dvv = dout[(size_t)i*DMOD + c];
      const float vv  = vwin[62+ii][t];
      mixv[ii] = pr[0]*as[q2] + pr[1]*am[q2] + pr[2]*alg[q2] + pr[3]*dvv + pr[4]*vv;
    }
  }
  const int lane = t & 63, wvw = t >> 6;
  #pragma unroll
  for (int ii=0;ii<16;ii++){
    float ss = mixv[ii]*mixv[ii];
    #pragma unroll
    for (int m=1;m<64;m<<=1) ss += __shfl_xor(ss, m, 64);
    if (lane == 0) red[ii][wvw] = ss;
  }
  __syncthreads();
  #pragma unroll
  for (int ii=0;ii<16;ii++){
    const float tot = red[ii][0]+red[ii][1]+red[ii][2]+red[ii][3];
    const float o = mixv[ii] * rsqrtf(tot*(1.f/256.f) + 1e-5f) * normw[t];
    omixb[(size_t)(i0+ii)*DMOD + c] = f2bf(o);
  }
}

// ---------------- launch ----------------
extern "C" void kernel_launch(void* const* d_in, const int* in_sizes, int n_in,
                              void* d_out, int out_size, void* d_ws, size_t ws_size,
                              hipStream_t stream)
{
  const float* hidden = (const float*)d_in[0];
  const float* Wq     = (const float*)d_in[1];
  const float* Wk     = (const float*)d_in[2];
  const float* Wv     = (const float*)d_in[3];
  const float* Wb     = (const float*)d_in[4];
  const float* convq  = (const float*)d_in[5];
  const float* convk  = (const float*)d_in[6];
  const float* convv  = (const float*)d_in[7];
  const float* firs   = (const float*)d_in[8];
  const float* firm   = (const float*)d_in[9];
  const float* firl   = (const float*)d_in[10];
  const float* gatew  = (const float*)d_in[11];
  const float* gateb  = (const float*)d_in[12];
  const float* logtemp= (const float*)d_in[13];
  const float* epsp   = (const float*)d_in[14];
  const float* normw  = (const float*)d_in[15];
  const float* Wo     = (const float*)d_in[16];
  float* out = (float*)d_out;

  char* W = (char*)d_ws;
  const size_t MB = (size_t)1 << 20;
  float* tmpq  = (float*)(W + 0*MB);     // 8MB; dob aliases after conv
  float* dob   = (float*)(W + 0*MB);
  float* tmpk  = (float*)(W + 8*MB);     // 8MB; ubuf aliases after conv
  float* ubuf  = (float*)(W + 8*MB);
  float* tmpv  = (float*)(W + 16*MB);    // 8MB; omixb aliases after conv
  u16*   omixb = (u16*)  (W + 16*MB);
  u16*   qb    = (u16*)  (W + 24*MB);    // 4MB bf16
  u16*   kb    = (u16*)  (W + 28*MB);    // 4MB
  u16*   vb    = (u16*)  (W + 32*MB);    // 4MB
  u16*   hidb  = (u16*)  (W + 36*MB);    // 4MB
  u16*   wqkvb = (u16*)  (W + 40*MB);    // 6MB
  u16*   wob   = (u16*)  (W + 46*MB);    // 2MB
  u16*   qbg   = (u16*)  (W + 48*MB);    // 4MB
  u16*   wng   = (u16*)  (W + 52*MB);    // 4MB
  u16*   kTg   = (u16*)  (W + 56*MB);    // 4MB
  u16*   atg   = (u16*)  (W + 60*MB);    // 0.5MB
  float* betab = (float*)(W + 60*MB + 524288);            // 32KB
  float* probs = (float*)(W + 60*MB + 524288 + 32768);    // 160KB
  float* ftl   = (float*)(W + 61*MB);                     // 252KB
  float* ftm   = (float*)(W + 61*MB + 300*1024);          // 60KB
  float* fts   = (float*)(W + 61*MB + 380*1024);          // 12KB

  cvt_all<<<6144, 256, 0, stream>>>(hidden, Wq, Wk, Wv, Wo, hidb, wqkvb, wob);
  prep_fir<<<324, 256, 0, stream>>>(firs, firm, firl, fts, ftm, ftl);

  gemm_qkv<<<dim3(16,24), 256, 0, stream>>>(hidb, wqkvb, tmpq, tmpk, tmpv);
  conv_silu3<<<24576, 256, 0, stream>>>(tmpq, tmpk, tmpv, convq, convk, convv, qb, kb, vb);

  beta_gate<<<2048, 256, 0, stream>>>(hidden, Wb, gatew, gateb, logtemp, epsp, betab, probs);

  delta_pre<<<dim3(64,4), 256, 0, stream>>>(qb, kb, vb, betab, qbg, wng, kTg, atg, ubuf);
  delta_scan_fused<<<dim3(16,4), 256, 0, stream>>>(qbg, wng, kTg, atg, ubuf, dob);

  fir_mix<<<dim3(128,4), 256, 0, stream>>>(vb, dob, probs, ftl, ftm, fts, normw, omixb);

  gemm_bf16<<<dim3(16,8), 256, 0, stream>>>(omixb, wob, out, LSEQ, DMOD, DMOD);
}

// Round 7
// 367.567 us; speedup vs baseline: 3.5295x; 3.5295x over previous
//
#include <hip/hip_runtime.h>

#define LSEQ 2048
#define DMOD 1024
#define NH   4
#define DH   256
#define NCH  64
#define CPAD 260

typedef unsigned short u16;
typedef short bf16x8 __attribute__((ext_vector_type(8)));
typedef float f32x4  __attribute__((ext_vector_type(4)));

#define MFMA16(a,b,c) __builtin_amdgcn_mfma_f32_16x16x32_bf16((a),(b),(c),0,0,0)

__device__ __forceinline__ float sigf(float x){ return 1.0f/(1.0f + expf(-x)); }

__device__ __forceinline__ u16 f2bf(float f){
  unsigned u = __float_as_uint(f);
  return (u16)((u + 0x7FFFu + ((u>>16)&1u)) >> 16);
}
__device__ __forceinline__ unsigned pk2(float a, float b){
  return (unsigned)f2bf(a) | ((unsigned)f2bf(b) << 16);
}
__device__ __forceinline__ float bf2f(u16 x){ return __uint_as_float(((unsigned)x)<<16); }

__device__ __forceinline__ void stage16(const void* g, void* l){
  __builtin_amdgcn_global_load_lds((const __attribute__((address_space(1))) unsigned*)g,
                                   (__attribute__((address_space(3))) unsigned*)l, 16, 0, 0);
}

// ---------------- merged fp32 -> bf16 convert (hidden + 4 weights) ----------------
__global__ __launch_bounds__(256) void cvt_all(
    const float* __restrict__ hidden, const float* __restrict__ Wq,
    const float* __restrict__ Wk, const float* __restrict__ Wv,
    const float* __restrict__ Wo, u16* __restrict__ hidb,
    u16* __restrict__ wqkvb, u16* __restrict__ wob)
{
  const int i4 = blockIdx.x*256 + threadIdx.x;   // 1.5M float4s
  const int e = i4*4;
  const float* src; u16* dst; int off;
  if (e < 2*1048576)      { src = hidden; dst = hidb;  off = e; }
  else if (e < 3*1048576) { src = Wq; dst = wqkvb; off = e - 2*1048576; }
  else if (e < 4*1048576) { src = Wk; dst = wqkvb + 1048576; off = e - 3*1048576; }
  else if (e < 5*1048576) { src = Wv; dst = wqkvb + 2*1048576; off = e - 4*1048576; }
  else                    { src = Wo; dst = wob; off = e - 5*1048576; }
  float4 v = *(const float4*)(src + off);
  *(uint2*)(dst + off) = make_uint2(pk2(v.x,v.y), pk2(v.z,v.w));
}

// ---------------- QKV GEMM: one launch, N=3072 split to 3 outputs ----------------
__global__ __launch_bounds__(256) void gemm_qkv(
    const u16* __restrict__ A, const u16* __restrict__ B,
    float* __restrict__ Cq, float* __restrict__ Ck, float* __restrict__ Cv)
{
  __shared__ __align__(16) u16 Asl[2][128][32];
  __shared__ __align__(16) u16 Bsl[2][128][32];
  const int i0 = blockIdx.x*128, j0 = blockIdx.y*128;
  const int t = threadIdx.x, lane = t & 63, wv = t >> 6;
  const int wm = wv >> 1, wn = wv & 1;
  const int li = lane & 15, g = lane >> 4;
  const int lr = lane >> 2, lc = lane & 3;
  f32x4 acc[4][4] = {};

  auto stageAB = [&](int buf, int kt){
    const int k0 = kt*32;
    #pragma unroll
    for (int c2=0;c2<2;c2++){
      const int row = wv*32 + c2*16 + lr;
      stage16(A + (size_t)(i0+row)*1024 + k0 + lc*8, &Asl[buf][wv*32 + c2*16][0]);
      stage16(B + (size_t)(j0+row)*1024 + k0 + lc*8, &Bsl[buf][wv*32 + c2*16][0]);
    }
  };

  int buf = 0;
  stageAB(0, 0);
  for (int kt=0; kt<32; kt++){
    __syncthreads();
    if (kt+1 < 32) stageAB(buf^1, kt+1);
    bf16x8 af[4], bf[4];
    #pragma unroll
    for (int mt=0;mt<4;mt++) af[mt] = *(const bf16x8*)&Asl[buf][wm*64+mt*16+li][g*8];
    #pragma unroll
    for (int nt=0;nt<4;nt++) bf[nt] = *(const bf16x8*)&Bsl[buf][wn*64+nt*16+li][g*8];
    #pragma unroll
    for (int mt=0;mt<4;mt++)
      #pragma unroll
      for (int nt=0;nt<4;nt++)
        acc[mt][nt] = MFMA16(af[mt], bf[nt], acc[mt][nt]);
    buf ^= 1;
  }
  float* C = (blockIdx.y < 8) ? Cq : (blockIdx.y < 16) ? Ck : Cv;
  const int jl = j0 & 1023;
  #pragma unroll
  for (int mt=0;mt<4;mt++){
    #pragma unroll
    for (int nt=0;nt<4;nt++){
      #pragma unroll
      for (int r=0;r<4;r++){
        const int row = i0 + wm*64 + mt*16 + g*4 + r;
        const int col = jl + wn*64 + nt*16 + li;
        C[(size_t)row*1024 + col] = acc[mt][nt][r];
      }
    }
  }
}

// ---------------- output GEMM: C[M][N]f32 = A[M][K] @ B[N][K]^T ----------------
__global__ __launch_bounds__(256) void gemm_bf16(
    const u16* __restrict__ A, const u16* __restrict__ B,
    float* __restrict__ C, int M, int N, int K)
{
  __shared__ __align__(16) u16 Asl[2][128][32];
  __shared__ __align__(16) u16 Bsl[2][128][32];
  const int i0 = blockIdx.x*128, j0 = blockIdx.y*128;
  const int t = threadIdx.x, lane = t & 63, wv = t >> 6;
  const int wm = wv >> 1, wn = wv & 1;
  const int li = lane & 15, g = lane >> 4;
  const int lr = lane >> 2, lc = lane & 3;
  f32x4 acc[4][4] = {};

  auto stageAB = [&](int buf, int kt){
    const int k0 = kt*32;
    #pragma unroll
    for (int c2=0;c2<2;c2++){
      const int row = wv*32 + c2*16 + lr;
      stage16(A + (size_t)(i0+row)*K + k0 + lc*8, &Asl[buf][wv*32 + c2*16][0]);
      stage16(B + (size_t)(j0+row)*K + k0 + lc*8, &Bsl[buf][wv*32 + c2*16][0]);
    }
  };

  int buf = 0;
  const int nk = K/32;
  stageAB(0, 0);
  for (int kt=0; kt<nk; kt++){
    __syncthreads();
    if (kt+1 < nk) stageAB(buf^1, kt+1);
    bf16x8 af[4], bf[4];
    #pragma unroll
    for (int mt=0;mt<4;mt++) af[mt] = *(const bf16x8*)&Asl[buf][wm*64+mt*16+li][g*8];
    #pragma unroll
    for (int nt=0;nt<4;nt++) bf[nt] = *(const bf16x8*)&Bsl[buf][wn*64+nt*16+li][g*8];
    #pragma unroll
    for (int mt=0;mt<4;mt++)
      #pragma unroll
      for (int nt=0;nt<4;nt++)
        acc[mt][nt] = MFMA16(af[mt], bf[nt], acc[mt][nt]);
    buf ^= 1;
  }
  #pragma unroll
  for (int mt=0;mt<4;mt++){
    #pragma unroll
    for (int nt=0;nt<4;nt++){
      #pragma unroll
      for (int r=0;r<4;r++){
        const int row = i0 + wm*64 + mt*16 + g*4 + r;
        const int col = j0 + wn*64 + nt*16 + li;
        C[(size_t)row*N + col] = acc[mt][nt][r];
      }
    }
  }
}

// ---------------- merged depthwise causal conv (K=4) + silu, bf16 out ----------------
__global__ __launch_bounds__(256) void conv_silu3(
    const float* __restrict__ tq, const float* __restrict__ tk, const float* __restrict__ tv,
    const float* __restrict__ wq, const float* __restrict__ wk, const float* __restrict__ wv2,
    u16* __restrict__ oq, u16* __restrict__ ok, u16* __restrict__ ov)
{
  const int idx = blockIdx.x*256 + threadIdx.x;
  const int which = idx >> 21;
  const int lidx = idx & ((1<<21)-1);
  const float* x = (which==0) ? tq : (which==1) ? tk : tv;
  const float* w = (which==0) ? wq : (which==1) ? wk : wv2;
  u16* y = (which==0) ? oq : (which==1) ? ok : ov;
  const int c = lidx & (DMOD-1);
  const int i = lidx >> 10;
  float4 wc = *(const float4*)(w + (size_t)c*4);
  float acc = wc.w * x[lidx];
  if (i >= 1) acc += wc.z * x[lidx -   DMOD];
  if (i >= 2) acc += wc.y * x[lidx - 2*DMOD];
  if (i >= 3) acc += wc.x * x[lidx - 3*DMOD];
  y[lidx] = f2bf(acc * sigf(acc));
}

// ---------------- beta (sigmoid) + 5-way gate probs per row ----------------
__global__ __launch_bounds__(256) void beta_gate(
    const float* __restrict__ hidden, const float* __restrict__ Wb,
    const float* __restrict__ gw, const float* __restrict__ gb,
    const float* __restrict__ logtemp, const float* __restrict__ epsp,
    float* __restrict__ betab, float* __restrict__ probs)
{
  const int i = blockIdx.x, t = threadIdx.x;
  float4 h4 = *(const float4*)(hidden + (size_t)i*DMOD + t*4);
  float part[24];
  #pragma unroll
  for (int o=0;o<24;o++){
    const float* wr = (o<4) ? (Wb + (size_t)o*DMOD) : (gw + (size_t)(o-4)*DMOD);
    float4 w4 = *(const float4*)(wr + t*4);
    part[o] = h4.x*w4.x + h4.y*w4.y + h4.z*w4.z + h4.w*w4.w;
  }
  __shared__ float red[24][4];
  __shared__ float fin[24];
  const int lane = t & 63, wv = t >> 6;
  #pragma unroll
  for (int o=0;o<24;o++){
    float vv = part[o];
    #pragma unroll
    for (int m=1;m<64;m<<=1) vv += __shfl_xor(vv, m, 64);
    if (lane == 0) red[o][wv] = vv;
  }
  __syncthreads();
  if (t < 24) fin[t] = red[t][0]+red[t][1]+red[t][2]+red[t][3];
  __syncthreads();
  if (t < NH){
    const int hh = t;
    betab[(size_t)i*NH + hh] = sigf(fin[hh]);
    float temp = expf(logtemp[hh]);
    float lg[5], mx = -1e30f;
    #pragma unroll
    for (int p=0;p<5;p++){ lg[p] = (fin[4+hh*5+p] + gb[hh*5+p]) / temp; mx = fmaxf(mx, lg[p]); }
    float ex[5], s = 0.f;
    #pragma unroll
    for (int p=0;p<5;p++){ ex[p] = expf(lg[p]-mx); s += ex[p]; }
    float eps = fminf(fmaxf(epsp[hh], 0.f), 0.2f);
    #pragma unroll
    for (int p=0;p<5;p++) probs[((size_t)i*NH+hh)*5 + p] = (ex[p]/s)*(1.f-5.f*eps) + eps;
  }
}

// ---------------- delta precompute: per (chunk, head), bf16 q/k/v inputs ----------------
__global__ __launch_bounds__(256) void delta_pre(
    const u16* __restrict__ q, const u16* __restrict__ k, const u16* __restrict__ v,
    const float* __restrict__ beta,
    u16* __restrict__ qbg, u16* __restrict__ wng, u16* __restrict__ kTg,
    u16* __restrict__ atg, float* __restrict__ ubuf)
{
  const int n = blockIdx.x, h = blockIdx.y;
  const int t = threadIdx.x;
  __shared__ float q_s[32][CPAD], k_s[32][CPAD], v_s[32][CPAD];
  __shared__ float T_s[32][32], Tb_s[32][32], M_s[32][32];
  __shared__ float rr[2][32][8];
  __shared__ float scl[2][32];
  __shared__ float bet_s[32];

  const int row = t >> 3, cq = t & 7;
  const size_t gb = (size_t)(n*32+row)*DMOD + h*DH + cq*32;
  const size_t cb = (size_t)(h*NCH+n)*32*256;
  const int sw = (row & 7) << 3;
  float psq = 0.f, psk = 0.f;
  #pragma unroll
  for (int x=0;x<4;x++){
    uint4 qa = *(const uint4*)(q + gb + x*8);
    uint4 ka = *(const uint4*)(k + gb + x*8);
    uint4 va = *(const uint4*)(v + gb + x*8);
    const unsigned qw[4] = {qa.x,qa.y,qa.z,qa.w};
    const unsigned kw[4] = {ka.x,ka.y,ka.z,ka.w};
    const unsigned vw[4] = {va.x,va.y,va.z,va.w};
    #pragma unroll
    for (int e=0;e<4;e++){
      float q0 = bf2f((u16)(qw[e]&0xffff)), q1 = bf2f((u16)(qw[e]>>16));
      float k0 = bf2f((u16)(kw[e]&0xffff)), k1 = bf2f((u16)(kw[e]>>16));
      float v0 = bf2f((u16)(vw[e]&0xffff)), v1 = bf2f((u16)(vw[e]>>16));
      q_s[row][cq*32+x*8+e*2]   = q0; q_s[row][cq*32+x*8+e*2+1] = q1;
      k_s[row][cq*32+x*8+e*2]   = k0; k_s[row][cq*32+x*8+e*2+1] = k1;
      v_s[row][cq*32+x*8+e*2]   = v0; v_s[row][cq*32+x*8+e*2+1] = v1;
      psq += q0*q0 + q1*q1;
      psk += k0*k0 + k1*k1;
    }
  }
  rr[0][row][cq] = psq; rr[1][row][cq] = psk;
  if (t < 32) bet_s[t] = beta[(size_t)(n*32+t)*NH + h];
  __syncthreads();
  if (t < 64){
    const int wh = t >> 5, r = t & 31;
    float s = 1e-6f;
    #pragma unroll
    for (int x=0;x<8;x++) s += rr[wh][r][x];
    scl[wh][r] = rsqrtf(s);
  }
  __syncthreads();
  {
    const float sq = scl[0][row], sk2 = scl[1][row];
    #pragma unroll
    for (int x=0;x<8;x++){
      float4 qa = *(float4*)&q_s[row][cq*32+x*4];
      qa.x*=sq; qa.y*=sq; qa.z*=sq; qa.w*=sq;
      *(float4*)&q_s[row][cq*32+x*4] = qa;
      *(uint2*)&qbg[cb + (size_t)row*256 + ((cq*32 + x*4) ^ sw)] =
          make_uint2(pk2(qa.x,qa.y), pk2(qa.z,qa.w));
      float4 ka = *(float4*)&k_s[row][cq*32+x*4];
      ka.x*=sk2; ka.y*=sk2; ka.z*=sk2; ka.w*=sk2;
      *(float4*)&k_s[row][cq*32+x*4] = ka;
    }
  }
  __syncthreads();
  // kT bf16 [dk=256][c=32], u32-col swizzle c2 ^ ((row&3)<<2)
  {
    unsigned* kp = (unsigned*)(kTg + ((size_t)(h*NCH+n)*256 + t)*32);
    #pragma unroll
    for (int c2=0;c2<16;c2++)
      kp[c2 ^ ((t&3)<<2)] = pk2(k_s[2*c2][t], k_s[2*c2+1][t]);
  }
  // M matrix
  {
    const int c = t >> 3, m0 = (t & 7)*4;
    float d0=0.f,d1=0.f,d2=0.f,d3=0.f;
    for (int kk=0;kk<DH;kk+=4){
      float4 a  = *(const float4*)&k_s[c][kk];
      float4 b0 = *(const float4*)&k_s[m0+0][kk];
      float4 b1 = *(const float4*)&k_s[m0+1][kk];
      float4 b2 = *(const float4*)&k_s[m0+2][kk];
      float4 b3 = *(const float4*)&k_s[m0+3][kk];
      d0 += a.x*b0.x + a.y*b0.y + a.z*b0.z + a.w*b0.w;
      d1 += a.x*b1.x + a.y*b1.y + a.z*b1.z + a.w*b1.w;
      d2 += a.x*b2.x + a.y*b2.y + a.z*b2.z + a.w*b2.w;
      d3 += a.x*b3.x + a.y*b3.y + a.z*b3.z + a.w*b3.w;
    }
    const float bc = bet_s[c];
    M_s[c][m0+0] = (m0+0 < c) ? bc*d0 : ((m0+0==c)?1.f:0.f);
    M_s[c][m0+1] = (m0+1 < c) ? bc*d1 : ((m0+1==c)?1.f:0.f);
    M_s[c][m0+2] = (m0+2 < c) ? bc*d2 : ((m0+2==c)?1.f:0.f);
    M_s[c][m0+3] = (m0+3 < c) ? bc*d3 : ((m0+3==c)?1.f:0.f);
  }
  __syncthreads();
  if (t < 32){
    const int j = t;
    for (int c=0;c<32;c++){
      float s = (c==j) ? 1.f : 0.f;
      for (int m=0;m<c;m++) s -= M_s[c][m]*T_s[m][j];
      T_s[c][j] = s;
    }
  }
  __syncthreads();
  {
    const int c = t >> 3, m0 = (t & 7)*4;
    #pragma unroll
    for (int x=0;x<4;x++) Tb_s[c][m0+x] = T_s[c][m0+x]*bet_s[m0+x];
  }
  __syncthreads();
  // w = Tb @ k_s (emit -w bf16, swizzled); u = Tb @ v_s (fp32)
  {
    const int colb = (t & 7)*4;
    float4 aw[8] = {};
    float4 au[8] = {};
    for (int m=0;m<32;m++){
      const float tb = Tb_s[row][m];
      #pragma unroll
      for (int y=0;y<8;y++){
        float4 kv = *(const float4*)&k_s[m][colb + y*32];
        float4 vv = *(const float4*)&v_s[m][colb + y*32];
        aw[y].x += tb*kv.x; aw[y].y += tb*kv.y; aw[y].z += tb*kv.z; aw[y].w += tb*kv.w;
        au[y].x += tb*vv.x; au[y].y += tb*vv.y; au[y].z += tb*vv.z; au[y].w += tb*vv.w;
      }
    }
    const size_t ob = (size_t)(n*32+row)*DMOD + h*DH + colb;
    #pragma unroll
    for (int y=0;y<8;y++){
      *(uint2*)&wng[cb + (size_t)row*256 + ((colb + y*32) ^ sw)] =
          make_uint2(pk2(-aw[y].x,-aw[y].y), pk2(-aw[y].z,-aw[y].w));
      *(float4*)(ubuf + ob + y*32) = au[y];
    }
  }
  // attn = tril(q k^T) bf16 [c][c'], swizzle m0 ^ ((c&3)<<3)
  {
    const int c = t >> 3, m0 = (t & 7)*4;
    float d0=0.f,d1=0.f,d2=0.f,d3=0.f;
    for (int kk=0;kk<DH;kk+=4){
      float4 a  = *(const float4*)&q_s[c][kk];
      float4 b0 = *(const float4*)&k_s[m0+0][kk];
      float4 b1 = *(const float4*)&k_s[m0+1][kk];
      float4 b2 = *(const float4*)&k_s[m0+2][kk];
      float4 b3 = *(const float4*)&k_s[m0+3][kk];
      d0 += a.x*b0.x + a.y*b0.y + a.z*b0.z + a.w*b0.w;
      d1 += a.x*b1.x + a.y*b1.y + a.z*b1.z + a.w*b1.w;
      d2 += a.x*b2.x + a.y*b2.y + a.z*b2.z + a.w*b2.w;
      d3 += a.x*b3.x + a.y*b3.y + a.z*b3.z + a.w*b3.w;
    }
    d0 = (m0+0 <= c) ? d0 : 0.f;
    d1 = (m0+1 <= c) ? d1 : 0.f;
    d2 = (m0+2 <= c) ? d2 : 0.f;
    d3 = (m0+3 <= c) ? d3 : 0.f;
    *(uint2*)&atg[((size_t)(h*NCH+n)*32 + c)*32 + (m0 ^ ((c&3)<<3))] =
        make_uint2(pk2(d0,d1), pk2(d2,d3));
  }
}

// ---------------- fused delta scan v6: v5 structure, rule-#20 fixed ----------------
// 4 waves: cs = wv&1 (c-half), j = wv>>1. All register-array indices compile-time
// (wave-uniform if(j==0)/else branches). 2 barriers/chunk, counted vmcnt(2).
__global__ __launch_bounds__(256) void delta_scan_fused(
    const u16* __restrict__ qbg, const u16* __restrict__ wng,
    const u16* __restrict__ kTg, const u16* __restrict__ atg,
    const float* __restrict__ ubuf, float* __restrict__ dob)
{
  const int qd = blockIdx.x, h = blockIdx.y;
  const int t = threadIdx.x, lane = t & 63, wv = t >> 6;
  const int cs = wv & 1, j = wv >> 1;
  const int g = lane >> 4, li = lane & 15;
  const int swz = (li & 7) << 3;
  const int kswz = (li & 3) << 3;

  __shared__ __align__(16) unsigned char stg[2][53248];
  __shared__ __align__(16) u16 ST[16][264];
  __shared__ __align__(16) u16 uaT[16][40];
  __shared__ __align__(16) float pfo[2][2][64][4];   // [j][cs][lane][4]

  f32x4 S[4];
  #pragma unroll
  for (int i=0;i<4;i++) S[i] = (f32x4){0.f,0.f,0.f,0.f};
  for (int i=t; i<16*264; i+=256) (&ST[0][0])[i] = 0;

  auto issue_stage = [&](int nn, int b){
    char* L = (char*)&stg[b][0];
    const size_t cbB = (size_t)(h*NCH+nn)*16384;
    #pragma unroll
    for (int jj=0;jj<13;jj++){
      const int s = wv*13 + jj;
      if (s < 48){
        const char* gsc = (s<16) ? (const char*)wng + cbB + (size_t)s*1024
                       : (s<32) ? (const char*)qbg + cbB + (size_t)(s-16)*1024
                                : (const char*)kTg + cbB + (size_t)(s-32)*1024;
        stage16(gsc + (size_t)lane*16, L + s*1024);
      } else if (s < 50){
        stage16((const char*)atg + (size_t)(h*NCH+nn)*2048 + (size_t)(s-48)*1024 + (size_t)lane*16,
                L + 49152 + (s-48)*1024);
      } else {
        const int i2 = s - 50;
        stage16(ubuf + (size_t)(nn*32 + i2*16 + (lane>>2))*DMOD + h*DH + qd*16 + (lane&3)*4,
                L + 51200 + i2*1024);
      }
    }
  };

  issue_stage(0, 0);

  for (int n=0;n<NCH;n++){
    const int b = n & 1;
    if (n == 0) asm volatile("s_waitcnt vmcnt(0)" ::: "memory");
    else        asm volatile("s_waitcnt vmcnt(2)" ::: "memory");
    asm volatile("s_waitcnt lgkmcnt(0)" ::: "memory");
    __builtin_amdgcn_s_barrier();                       // B1: buffer + ST ready
    __builtin_amdgcn_sched_barrier(0);
    issue_stage((n+1 < NCH) ? n+1 : NCH-1, b^1);

    const char* L = (const char*)&stg[b][0];
    const u16*  wl = (const u16*)(L);
    const u16*  ql = (const u16*)(L + 16384);
    const u16*  kl = (const u16*)(L + 32768);
    const u16*  al = (const u16*)(L + 49152);
    const float* ul = (const float*)(L + 51200);

    // ---- full S^T B-frags ----
    bf16x8 Bs[8];
    #pragma unroll
    for (int kb=0;kb<8;kb++)
      Bs[kb] = *(const bf16x8*)&ST[li][kb*32 + g*8];

    // ---- ua = u - w @ S (full dk, c-half cs; chain split 2x4) ----
    f32x4 ua;
    #pragma unroll
    for (int r=0;r<4;r++)
      ua[r] = ul[(cs*16 + g*4 + r)*16 + li];
    f32x4 x2 = (f32x4){0.f,0.f,0.f,0.f};
    #pragma unroll
    for (int kb=0;kb<4;kb++){
      const int idx = (kb*32 + g*8) ^ swz;
      bf16x8 aw = *(const bf16x8*)&wl[(size_t)(cs*16+li)*256 + idx];
      ua = MFMA16(aw, Bs[kb], ua);
    }
    #pragma unroll
    for (int kb=4;kb<8;kb++){
      const int idx = (kb*32 + g*8) ^ swz;
      bf16x8 aw = *(const bf16x8*)&wl[(size_t)(cs*16+li)*256 + idx];
      x2 = MFMA16(aw, Bs[kb], x2);
    }
    #pragma unroll
    for (int r=0;r<4;r++) ua[r] += x2[r];

    // ---- op = q @ S (dk-half j, c-half cs) — compile-time Bs indices ----
    f32x4 op = (f32x4){0.f,0.f,0.f,0.f};
    if (j == 0){
      #pragma unroll
      for (int kb=0;kb<4;kb++){
        const int idx = (kb*32 + g*8) ^ swz;
        bf16x8 aq = *(const bf16x8*)&ql[(size_t)(cs*16+li)*256 + idx];
        op = MFMA16(aq, Bs[kb], op);
      }
    } else {
      #pragma unroll
      for (int kb2=0;kb2<4;kb2++){
        const int idx = ((4+kb2)*32 + g*8) ^ swz;
        bf16x8 aq = *(const bf16x8*)&ql[(size_t)(cs*16+li)*256 + idx];
        op = MFMA16(aq, Bs[4+kb2], op);
      }
    }
    *(f32x4*)&pfo[j][cs][lane][0] = op;

    // ---- uaT split-write (j0: elems 0,1; j1: elems 2,3) ----
    if (j == 0) *(unsigned*)&uaT[li][cs*16 + g*4]     = pk2(ua[0], ua[1]);
    else        *(unsigned*)&uaT[li][cs*16 + g*4 + 2] = pk2(ua[2], ua[3]);
    asm volatile("s_waitcnt lgkmcnt(0)" ::: "memory");
    __builtin_amdgcn_s_barrier();                       // B2: uaT + pfo ready
    __builtin_amdgcn_sched_barrier(0);

    bf16x8 bu = *(const bf16x8*)&uaT[li][g*8];

    // ---- S += kT @ ua (dk-quarter wv) + ST refresh ----
    #pragma unroll
    for (int mtl=0;mtl<4;mtl++){
      const int rowk = (wv*4+mtl)*16 + li;
      bf16x8 a = *(const bf16x8*)&kl[(size_t)rowk*32 + ((g*8) ^ kswz)];
      S[mtl] = MFMA16(a, bu, S[mtl]);
    }
    #pragma unroll
    for (int mtl=0;mtl<4;mtl++)
      *(uint2*)&ST[li][(wv*4+mtl)*16 + g*4] =
          make_uint2(pk2(S[mtl][0],S[mtl][1]), pk2(S[mtl][2],S[mtl][3]));

    // ---- attn @ ua (redundant, own c-half) ----
    f32x4 atp = (f32x4){0.f,0.f,0.f,0.f};
    {
      bf16x8 a = *(const bf16x8*)&al[(size_t)(cs*16+li)*32 + ((g*8) ^ kswz)];
      atp = MFMA16(a, bu, atp);
    }

    // ---- o = op + pfo[other dk-half] + atp ; compile-time element indices ----
    {
      f32x4 oq = *(const f32x4*)&pfo[j^1][cs][lane][0];
      const size_t ob = (size_t)(n*32 + cs*16)*DMOD + h*DH + qd*16 + li;
      if (j == 0){
        dob[ob + (size_t)(g*4+0)*DMOD] = op[0] + oq[0] + atp[0];
        dob[ob + (size_t)(g*4+1)*DMOD] = op[1] + oq[1] + atp[1];
      } else {
        dob[ob + (size_t)(g*4+2)*DMOD] = op[2] + oq[2] + atp[2];
        dob[ob + (size_t)(g*4+3)*DMOD] = op[3] + oq[3] + atp[3];
      }
    }
  }
}

// ---------------- transpose FIR filters to [j][c] ----------------
__global__ void prep_fir(const float* __restrict__ fs, const float* __restrict__ fm,
                         const float* __restrict__ fl, float* __restrict__ fts,
                         float* __restrict__ ftm, float* __restrict__ ftl)
{
  const int idx = blockIdx.x*256 + threadIdx.x;
  if (idx < 63*1024){
    const int j = idx >> 10, c = idx & 1023;
    ftl[idx] = fl[(size_t)c*63 + j];
  } else if (idx < 78*1024){
    const int r = idx - 63*1024;
    const int j = r >> 10, c = r & 1023;
    ftm[r] = fm[(size_t)c*15 + j];
  } else {
    const int r = idx - 78*1024;
    const int j = r >> 10, c = r & 1023;
    fts[r] = fs[(size_t)c*3 + j];
  }
}

// ---------------- FIR + gated mix + RMSNorm, LDS-windowed (16 rows/block) ----------------
__global__ __launch_bounds__(256) void fir_mix(
    const u16* __restrict__ vb, const float* __restrict__ dout,
    const float* __restrict__ probs, const float* __restrict__ ftl,
    const float* __restrict__ ftm, const float* __restrict__ fts,
    const float* __restrict__ normw, u16* __restrict__ omixb)
{
  const int i0 = blockIdx.x*16, h = blockIdx.y;
  const int t = threadIdx.x;
  const int c = h*DH + t;
  __shared__ float vwin[78][256];
  __shared__ float red[16][4];

  for (int ll=0; ll<78; ll++){
    const int row = i0 - 62 + ll;
    vwin[ll][t] = (row >= 0) ? bf2f(vb[(size_t)row*DMOD + c]) : 0.f;
  }
  __syncthreads();

  float mixv[16];
  #pragma unroll
  for (int cch=0; cch<4; cch++){
    float as[4] = {0,0,0,0}, am[4] = {0,0,0,0}, alg[4] = {0,0,0,0};
    for (int jt=0; jt<63; jt++){
      const float f = ftl[(size_t)jt*DMOD + c];
      #pragma unroll
      for (int q2=0;q2<4;q2++) alg[q2] += f * vwin[cch*4+q2 + jt][t];
    }
    #pragma unroll
    for (int jt=0; jt<15; jt++){
      const float f = ftm[(size_t)jt*DMOD + c];
      #pragma unroll
      for (int q2=0;q2<4;q2++) am[q2] += f * vwin[cch*4+q2 + 48 + jt][t];
    }
    #pragma unroll
    for (int jt=0; jt<3; jt++){
      const float f = fts[(size_t)jt*DMOD + c];
      #pragma unroll
      for (int q2=0;q2<4;q2++) as[q2] += f * vwin[cch*4+q2 + 60 + jt][t];
    }
    #pragma unroll
    for (int q2=0;q2<4;q2++){
      const int ii = cch*4+q2;
      const int i = i0+ii;
      const float* pr = probs + ((size_t)i*NH + h)*5;
      const float dvv = dout[(size_t)i*DMOD + c];
      const float vv  = vwin[62+ii][t];
      mixv[ii] = pr[0]*as[q2] + pr[1]*am[q2] + pr[2]*alg[q2] + pr[3]*dvv + pr[4]*vv;
    }
  }
  const int lane = t & 63, wvw = t >> 6;
  #pragma unroll
  for (int ii=0;ii<16;ii++){
    float ss = mixv[ii]*mixv[ii];
    #pragma unroll
    for (int m=1;m<64;m<<=1) ss += __shfl_xor(ss, m, 64);
    if (lane == 0) red[ii][wvw] = ss;
  }
  __syncthreads();
  #pragma unroll
  for (int ii=0;ii<16;ii++){
    const float tot = red[ii][0]+red[ii][1]+red[ii][2]+red[ii][3];
    const float o = mixv[ii] * rsqrtf(tot*(1.f/256.f) + 1e-5f) * normw[t];
    omixb[(size_t)(i0+ii)*DMOD + c] = f2bf(o);
  }
}

// ---------------- launch ----------------
extern "C" void kernel_launch(void* const* d_in, const int* in_sizes, int n_in,
                              void* d_out, int out_size, void* d_ws, size_t ws_size,
                              hipStream_t stream)
{
  const float* hidden = (const float*)d_in[0];
  const float* Wq     = (const float*)d_in[1];
  const float* Wk     = (const float*)d_in[2];
  const float* Wv     = (const float*)d_in[3];
  const float* Wb     = (const float*)d_in[4];
  const float* convq  = (const float*)d_in[5];
  const float* convk  = (const float*)d_in[6];
  const float* convv  = (const float*)d_in[7];
  const float* firs   = (const float*)d_in[8];
  const float* firm   = (const float*)d_in[9];
  const float* firl   = (const float*)d_in[10];
  const float* gatew  = (const float*)d_in[11];
  const float* gateb  = (const float*)d_in[12];
  const float* logtemp= (const float*)d_in[13];
  const float* epsp   = (const float*)d_in[14];
  const float* normw  = (const float*)d_in[15];
  const float* Wo     = (const float*)d_in[16];
  float* out = (float*)d_out;

  char* W = (char*)d_ws;
  const size_t MB = (size_t)1 << 20;
  float* tmpq  = (float*)(W + 0*MB);     // 8MB; dob aliases after conv
  float* dob   = (float*)(W + 0*MB);
  float* tmpk  = (float*)(W + 8*MB);     // 8MB; ubuf aliases after conv
  float* ubuf  = (float*)(W + 8*MB);
  float* tmpv  = (float*)(W + 16*MB);    // 8MB; omixb aliases after conv
  u16*   omixb = (u16*)  (W + 16*MB);
  u16*   qb    = (u16*)  (W + 24*MB);    // 4MB bf16
  u16*   kb    = (u16*)  (W + 28*MB);    // 4MB
  u16*   vb    = (u16*)  (W + 32*MB);    // 4MB
  u16*   hidb  = (u16*)  (W + 36*MB);    // 4MB
  u16*   wqkvb = (u16*)  (W + 40*MB);    // 6MB
  u16*   wob   = (u16*)  (W + 46*MB);    // 2MB
  u16*   qbg   = (u16*)  (W + 48*MB);    // 4MB
  u16*   wng   = (u16*)  (W + 52*MB);    // 4MB
  u16*   kTg   = (u16*)  (W + 56*MB);    // 4MB
  u16*   atg   = (u16*)  (W + 60*MB);    // 0.5MB
  float* betab = (float*)(W + 60*MB + 524288);            // 32KB
  float* probs = (float*)(W + 60*MB + 524288 + 32768);    // 160KB
  float* ftl   = (float*)(W + 61*MB);                     // 252KB
  float* ftm   = (float*)(W + 61*MB + 300*1024);          // 60KB
  float* fts   = (float*)(W + 61*MB + 380*1024);          // 12KB

  cvt_all<<<6144, 256, 0, stream>>>(hidden, Wq, Wk, Wv, Wo, hidb, wqkvb, wob);
  prep_fir<<<324, 256, 0, stream>>>(firs, firm, firl, fts, ftm, ftl);

  gemm_qkv<<<dim3(16,24), 256, 0, stream>>>(hidb, wqkvb, tmpq, tmpk, tmpv);
  conv_silu3<<<24576, 256, 0, stream>>>(tmpq, tmpk, tmpv, convq, convk, convv, qb, kb, vb);

  beta_gate<<<2048, 256, 0, stream>>>(hidden, Wb, gatew, gateb, logtemp, epsp, betab, probs);

  delta_pre<<<dim3(64,4), 256, 0, stream>>>(qb, kb, vb, betab, qbg, wng, kTg, atg, ubuf);
  delta_scan_fused<<<dim3(16,4), 256, 0, stream>>>(qbg, wng, kTg, atg, ubuf, dob);

  fir_mix<<<dim3(128,4), 256, 0, stream>>>(vb, dob, probs, ftl, ftm, fts, normw, omixb);

  gemm_bf16<<<dim3(16,8), 256, 0, stream>>>(omixb, wob, out, LSEQ, DMOD, DMOD);
}